// Round 15
// baseline (473.052 us; speedup 1.0000x reference)
//
#include <hip/hip_runtime.h>
#include <math.h>

#define NN   50000
#define NE   800000
#define FEATD 128
#define SED  16
#define HD   64
#define NCLS 10
#define NLAY 3
#define NG   500

// two-level counting sort params
#define CHUNK 4096
#define NCH   ((NE + CHUNK - 1) / CHUNK)  // 196
#define CBSH  9
#define CB    ((NN + (1 << CBSH) - 1) >> CBSH)  // 98

typedef short  v8s __attribute__((ext_vector_type(8)));
typedef float  v4f __attribute__((ext_vector_type(4)));

// ---- bf16 helpers ---------------------------------------------------------
__device__ inline unsigned short f2bf(float f){
    unsigned int u = __float_as_uint(f);
    u += 0x7fffu + ((u >> 16) & 1u);
    return (unsigned short)(u >> 16);
}
__device__ inline unsigned int pack2bf(float a, float b){
    return (unsigned int)f2bf(a) | ((unsigned int)f2bf(b) << 16);
}
__device__ inline float bf_lo(unsigned int p){ return __uint_as_float(p << 16); }
__device__ inline float bf_hi(unsigned int p){ return __uint_as_float(p & 0xffff0000u); }

// ---------------- utility ---------------------------------------------------
__global__ void zero_f32(float* __restrict__ p, int n){
    int i = blockIdx.x*blockDim.x + threadIdx.x;
    if (i < n) p[i] = 0.f;
}

// ---------------- weight prep: bf16 + transpose to WT[n][k] ----------------
__global__ __launch_bounds__(256) void wprep(
        const float* __restrict__ gcn_W, const float* __restrict__ gin_W1,
        const float* __restrict__ gin_W2, const float* __restrict__ whp_W,
        unsigned short* __restrict__ gcnWT, unsigned short* __restrict__ W1T,
        unsigned short* __restrict__ W2T,  unsigned short* __restrict__ whpWT)
{
    int i = blockIdx.x*256 + threadIdx.x;
    if (i < 12288){
        int li = i / 4096, r = i % 4096, nn = r / 64, kk = r % 64;
        gcnWT[li*4096 + nn*64 + kk] = f2bf(gcn_W[li*4096 + kk*64 + nn]);
    } else if (i < 36864){
        int j = i - 12288; int li = j / 8192, r = j % 8192, nn = r / 128, kk = r % 128;
        W1T[li*8192 + nn*128 + kk] = f2bf(gin_W1[li*8192 + kk*64 + nn]);
    } else if (i < 49152){
        int j = i - 36864; int li = j / 4096, r = j % 4096, nn = r / 64, kk = r % 64;
        W2T[li*4096 + nn*64 + kk] = f2bf(gin_W2[li*4096 + kk*64 + nn]);
    } else if (i < 57344){
        int j = i - 49152; int nn = j / 128, kk = j % 128;
        whpWT[nn*128 + kk] = f2bf(whp_W[kk*64 + nn]);
    }
}

// ---------------- two-level counting sort of edges by dst ------------------
__global__ __launch_bounds__(256) void coarse_hist(
        const int* __restrict__ dst, int* __restrict__ ghist){
    __shared__ int h[CB];
    for (int i = threadIdx.x; i < CB; i += 256) h[i] = 0;
    __syncthreads();
    int base = blockIdx.x * CHUNK;
    int end  = base + CHUNK; if (end > NE) end = NE;
    for (int i = base + threadIdx.x; i < end; i += 256)
        atomicAdd(&h[dst[i] >> CBSH], 1);
    __syncthreads();
    for (int i = threadIdx.x; i < CB; i += 256)
        ghist[(size_t)blockIdx.x * CB + i] = h[i];
}

// LDS-staged scan of ghist (196*98 ints = 77KB LDS); single-block kernel.
__global__ __launch_bounds__(256) void coarse_scan(int* __restrict__ ghist){
    __shared__ int sh[NCH * CB];
    __shared__ int sc[256];
    int t = threadIdx.x;
    for (int i = t; i < NCH * CB; i += 256) sh[i] = ghist[i];
    __syncthreads();
    int run = 0;
    if (t < CB){
        for (int c = 0; c < NCH; c++){
            int v = sh[c*CB + t];
            sh[c*CB + t] = run;
            run += v;
        }
    }
    sc[t] = (t < CB) ? run : 0;
    __syncthreads();
    for (int d = 1; d < 256; d <<= 1){
        int u = (t >= d) ? sc[t-d] : 0;
        __syncthreads();
        sc[t] += u;
        __syncthreads();
    }
    int bstart = (t == 0) ? 0 : sc[t-1];
    if (t < CB){
        for (int c = 0; c < NCH; c++) sh[c*CB + t] += bstart;
    }
    __syncthreads();
    for (int i = t; i < NCH * CB; i += 256) ghist[i] = sh[i];
}

__global__ __launch_bounds__(256) void bin_lds(
        const int* __restrict__ src, const int* __restrict__ dst,
        const int* __restrict__ ghist, unsigned int* __restrict__ ebuf){
    __shared__ unsigned int lbuf[CHUNK];
    __shared__ unsigned int lbuf2[CHUNK];
    __shared__ int hist[CB], lstart[CB], cursor[CB], gbase[CB];
    __shared__ int sc[256];
    int t = threadIdx.x, c = blockIdx.x;
    for (int i = t; i < CB; i += 256){
        hist[i] = 0;
        gbase[i] = ghist[(size_t)c*CB + i];
    }
    __syncthreads();
    int base = c * CHUNK;
    int nend = base + CHUNK; if (nend > NE) nend = NE;
    nend -= base;
    for (int i = t; i < nend; i += 256){
        int d = dst[base + i];
        lbuf[i] = (unsigned int)src[base + i] | ((unsigned int)d << 16);
        atomicAdd(&hist[d >> CBSH], 1);
    }
    __syncthreads();
    sc[t] = (t < CB) ? hist[t] : 0;
    __syncthreads();
    for (int d = 1; d < 256; d <<= 1){
        int u = (t >= d) ? sc[t-d] : 0;
        __syncthreads();
        sc[t] += u;
        __syncthreads();
    }
    if (t < CB){
        lstart[t] = sc[t] - hist[t];
        cursor[t] = sc[t] - hist[t];
    }
    __syncthreads();
    for (int i = t; i < nend; i += 256){
        unsigned int u = lbuf[i];
        int b = (int)(u >> 16) >> CBSH;
        int p = atomicAdd(&cursor[b], 1);
        lbuf2[p] = u;
    }
    __syncthreads();
    for (int p = t; p < nend; p += 256){
        unsigned int u = lbuf2[p];
        int b = (int)(u >> 16) >> CBSH;
        ebuf[gbase[b] + (p - lstart[b])] = u;
    }
}

__global__ __launch_bounds__(256) void scatter_all(
        const unsigned int* __restrict__ ebuf, const int* __restrict__ ghist,
        int* __restrict__ off, float* __restrict__ dinv,
        int* __restrict__ csr, int n){
    __shared__ int lcnt[512];
    __shared__ int lex[512];
    __shared__ int sc[256];
    int t = threadIdx.x, b = blockIdx.x;
    int n0 = b << CBSH;
    int nn = n - n0; if (nn > 512) nn = 512;
    int lo = ghist[b];
    int hi = (b + 1 < CB) ? ghist[b + 1] : NE;
    lcnt[t] = 0; lcnt[t + 256] = 0;
    __syncthreads();
    for (int j = lo + t; j < hi; j += 256)
        atomicAdd(&lcnt[(int)(ebuf[j] >> 16) - n0], 1);
    __syncthreads();
    int c0 = lcnt[2*t], c1 = lcnt[2*t+1];
    sc[t] = c0 + c1;
    __syncthreads();
    for (int d = 1; d < 256; d <<= 1){
        int u = (t >= d) ? sc[t-d] : 0;
        __syncthreads();
        sc[t] += u;
        __syncthreads();
    }
    int bse = sc[t] - (c0 + c1);
    lex[2*t]   = bse;
    lex[2*t+1] = bse + c0;
    __syncthreads();
    for (int i = t; i < nn; i += 256){
        off[n0 + i]  = lo + lex[i];
        dinv[n0 + i] = rsqrtf((float)lcnt[i] + 1.0f);
    }
    if (b == 0 && t == 0) off[n] = NE;
    __syncthreads();
    for (int j = lo + t; j < hi; j += 256){
        unsigned int u = ebuf[j];
        int d = (int)(u >> 16) - n0;
        int p = atomicAdd(&lex[d], 1);
        csr[lo + p] = (int)(u & 0xffffu);
    }
}

// ---------------- fused pre+emb: xcb0 = bf16([x@preW+b | s@embW+b]) -------
__global__ __launch_bounds__(256) void pre_emb(
        const float* __restrict__ x, const float* __restrict__ preW,
        const float* __restrict__ preb,
        const float* __restrict__ s, const float* __restrict__ embW,
        const float* __restrict__ embb,
        unsigned short* __restrict__ xcb, int n)
{
    __shared__ float atx[64 * 132];
    __shared__ float ats[64 * 20];
    int tid = threadIdx.x;
    int r0  = blockIdx.x * 64;
    for (int idx = tid; idx < 64 * 32; idx += 256){
        int row = idx >> 5, kq = idx & 31;
        float4 v = make_float4(0.f, 0.f, 0.f, 0.f);
        if (r0 + row < n) v = *(const float4*)(x + (size_t)(r0 + row) * 128 + kq * 4);
        *(float4*)(&atx[row * 132 + kq * 4]) = v;
    }
    for (int idx = tid; idx < 64 * 4; idx += 256){
        int row = idx >> 2, kq = idx & 3;
        float4 v = make_float4(0.f, 0.f, 0.f, 0.f);
        if (r0 + row < n) v = *(const float4*)(s + (size_t)(r0 + row) * 16 + kq * 4);
        *(float4*)(&ats[row * 20 + kq * 4]) = v;
    }
    __syncthreads();
    int lane = tid & 63;
    int c0 = __builtin_amdgcn_readfirstlane((tid >> 6) << 4);
    int row = r0 + lane;
    if (row >= n) return;
    float acc[16];
#pragma unroll
    for (int j = 0; j < 16; j++) acc[j] = 0.f;
    for (int k = 0; k < 128; k += 4){
        float4 av = *(const float4*)(&atx[lane * 132 + k]);
        float aa[4] = {av.x, av.y, av.z, av.w};
#pragma unroll
        for (int kk = 0; kk < 4; kk++){
            const float* wr = preW + (k + kk) * 64 + c0;
#pragma unroll
            for (int j = 0; j < 16; j++)
                acc[j] = fmaf(aa[kk], wr[j], acc[j]);
        }
    }
#pragma unroll
    for (int j = 0; j < 16; j++) acc[j] += preb[c0 + j];
    unsigned int pk[8];
#pragma unroll
    for (int j = 0; j < 8; j++) pk[j] = pack2bf(acc[2*j], acc[2*j+1]);
    {
        unsigned short* ob = xcb + (size_t)row * 128 + c0;
        uint4 u0; u0.x = pk[0]; u0.y = pk[1]; u0.z = pk[2]; u0.w = pk[3];
        uint4 u1; u1.x = pk[4]; u1.y = pk[5]; u1.z = pk[6]; u1.w = pk[7];
        *(uint4*)(ob)     = u0;
        *(uint4*)(ob + 8) = u1;
    }
#pragma unroll
    for (int j = 0; j < 16; j++) acc[j] = 0.f;
    for (int k = 0; k < 16; k += 4){
        float4 av = *(const float4*)(&ats[lane * 20 + k]);
        float aa[4] = {av.x, av.y, av.z, av.w};
#pragma unroll
        for (int kk = 0; kk < 4; kk++){
            const float* wr = embW + (k + kk) * 64 + c0;
#pragma unroll
            for (int j = 0; j < 16; j++)
                acc[j] = fmaf(aa[kk], wr[j], acc[j]);
        }
    }
#pragma unroll
    for (int j = 0; j < 16; j++) acc[j] += embb[c0 + j];
#pragma unroll
    for (int j = 0; j < 8; j++) pk[j] = pack2bf(acc[2*j], acc[2*j+1]);
    {
        unsigned short* ob = xcb + (size_t)row * 128 + 64 + c0;
        uint4 u0; u0.x = pk[0]; u0.y = pk[1]; u0.z = pk[2]; u0.w = pk[3];
        uint4 u1; u1.x = pk[4]; u1.y = pk[5]; u1.z = pk[6]; u1.w = pk[7];
        *(uint4*)(ob)     = u0;
        *(uint4*)(ob + 8) = u1;
    }
}

// ---------------- MFMA bf16 linear (whp): out fp32 -----------------------
template<int K>
__global__ __launch_bounds__(256) void mfma_linear(
        const unsigned short* __restrict__ A, int lda,
        const unsigned short* __restrict__ WT,
        const float* __restrict__ bias,
        float* __restrict__ out, int ldo, int n)
{
    constexpr int NKO = K / 32;
    int tid = threadIdx.x;
    int w = tid >> 6, l = tid & 63;
    int m = l & 15, q = l >> 4;
    int rbase = blockIdx.x * 64 + w * 16;
    int arow  = rbase + m;
    bool valid = arow < n;
    v8s a[NKO];
#pragma unroll
    for (int ko = 0; ko < NKO; ko++){
        v8s z = {0,0,0,0,0,0,0,0};
        a[ko] = valid ? *(const v8s*)(A + (size_t)arow * lda + ko*32 + q*8) : z;
    }
#pragma unroll
    for (int ct = 0; ct < 4; ct++){
        v4f acc = {0.f, 0.f, 0.f, 0.f};
#pragma unroll
        for (int ko = 0; ko < NKO; ko++){
            v8s b = *(const v8s*)(WT + (size_t)(ct*16 + m) * K + ko*32 + q*8);
            acc = __builtin_amdgcn_mfma_f32_16x16x32_bf16(a[ko], b, acc, 0, 0, 0);
        }
        int col = ct*16 + m;
        float bv = bias ? bias[col] : 0.f;
#pragma unroll
        for (int r = 0; r < 4; r++){
            int orow = rbase + q*4 + r;
            if (orow < n) out[(size_t)orow * ldo + col] = acc[r] + bv;
        }
    }
}

// ---------------- fused layer: gather (GIN+GCN) + 3 MFMA GEMMs -------------
// Per 64-node block: wave w gathers its 16 nodes into LDS tiles (wave-local),
// then runs GEMM3 (gcn), GEMM1+GEMM2 (GIN MLP) from LDS. No barriers needed:
// every LDS row is written and read by the same wave.
__global__ __launch_bounds__(256) void layer_fused(
        const unsigned int* __restrict__ xcb_cur,   // [n,64] packed bf16 pairs
        const float* __restrict__ dinv,
        const int* __restrict__ off, const int* __restrict__ csr,
        const unsigned short* __restrict__ W1T,     // [64][128]
        const float* __restrict__ b1,
        const unsigned short* __restrict__ W2T,     // [64][64]
        const float* __restrict__ b2,
        const unsigned short* __restrict__ gcnWT,   // [64][64]
        const float* __restrict__ gcnb,
        unsigned short* __restrict__ xcb_nxt, int n)
{
    __shared__ unsigned short hp[64 * 136];   // hpre tile (bf16), stride 136
    __shared__ unsigned short ut[64 * 72];    // u tile (bf16), stride 72
    __shared__ unsigned short hsh[64 * 72];   // h tile (bf16), stride 72
    int tid = threadIdx.x;
    int w = tid >> 6, l = tid & 63;
    int blk0 = blockIdx.x * 64;

    // ---- phase 1: gather 16 nodes (wave-wide per node) ----
    for (int nd = 0; nd < 16; nd++){
        int lrow = w*16 + nd;
        int node = blk0 + lrow;
        float a0 = 0.f, a1 = 0.f, u0 = 0.f, u1 = 0.f;
        if (node < n){
            int beg = off[node], end = off[node+1];
            unsigned int ps = xcb_cur[(size_t)node*64 + l];
            float s0f = bf_lo(ps), s1f = bf_hi(ps);
            a0 = s0f; a1 = s1f;
            float g0 = 0.f, g1 = 0.f;
            int e = beg;
            for (; e + 4 <= end; e += 4){
                int s0 = csr[e], s1 = csr[e+1], s2 = csr[e+2], s3 = csr[e+3];
                unsigned int p0 = xcb_cur[(size_t)s0*64 + l];
                unsigned int p1 = xcb_cur[(size_t)s1*64 + l];
                unsigned int p2 = xcb_cur[(size_t)s2*64 + l];
                unsigned int p3 = xcb_cur[(size_t)s3*64 + l];
                float d0 = dinv[s0], d1 = dinv[s1], d2 = dinv[s2], d3 = dinv[s3];
                float v0 = bf_lo(p0), v1 = bf_lo(p1), v2 = bf_lo(p2), v3 = bf_lo(p3);
                float w0 = bf_hi(p0), w1 = bf_hi(p1), w2 = bf_hi(p2), w3 = bf_hi(p3);
                a0 += (v0 + v1) + (v2 + v3);
                a1 += (w0 + w1) + (w2 + w3);
                g0 = fmaf(d0, v0, fmaf(d1, v1, fmaf(d2, v2, fmaf(d3, v3, g0))));
                g1 = fmaf(d0, w0, fmaf(d1, w1, fmaf(d2, w2, fmaf(d3, w3, g1))));
            }
            for (; e < end; e++){
                int s0 = csr[e];
                unsigned int p0 = xcb_cur[(size_t)s0*64 + l];
                float d0 = dinv[s0];
                float v0 = bf_lo(p0), w0 = bf_hi(p0);
                a0 += v0; a1 += w0;
                g0 = fmaf(d0, v0, g0);
                g1 = fmaf(d0, w0, g1);
            }
            float di = dinv[node];
            u0 = fmaf(di, g0, di*di*s0f);
            u1 = fmaf(di, g1, di*di*s1f);
        }
        *(unsigned int*)(&hp[lrow*136 + 2*l]) = pack2bf(a0, a1);
        if (l >= 32)
            *(unsigned int*)(&ut[lrow*72 + 2*(l - 32)]) = pack2bf(u0, u1);
    }

    // ---- phase 2: MFMA (all LDS reads wave-local) ----
    int m = l & 15, q = l >> 4;
    int rbase = blk0 + w*16;
    // GEMM3: s_new = tanh(u @ gcnW + b)
    {
        v8s a3[2];
#pragma unroll
        for (int ko = 0; ko < 2; ko++)
            a3[ko] = *(const v8s*)(&ut[(w*16 + m)*72 + ko*32 + q*8]);
#pragma unroll
        for (int ct = 0; ct < 4; ct++){
            v4f acc = {0.f, 0.f, 0.f, 0.f};
#pragma unroll
            for (int ko = 0; ko < 2; ko++){
                v8s b = *(const v8s*)(gcnWT + (size_t)(ct*16 + m) * 64 + ko*32 + q*8);
                acc = __builtin_amdgcn_mfma_f32_16x16x32_bf16(a3[ko], b, acc, 0, 0, 0);
            }
            int col = ct*16 + m;
            float bv = gcnb[col];
#pragma unroll
            for (int r = 0; r < 4; r++){
                int orow = rbase + q*4 + r;
                if (orow < n)
                    xcb_nxt[(size_t)orow * 128 + 64 + col] = f2bf(tanhf(acc[r] + bv));
            }
        }
    }
    // GEMM1: h = relu(hp @ W1 + b1) -> hsh
    {
        v8s a[4];
#pragma unroll
        for (int ko = 0; ko < 4; ko++)
            a[ko] = *(const v8s*)(&hp[(w*16 + m)*136 + ko*32 + q*8]);
#pragma unroll
        for (int ct = 0; ct < 4; ct++){
            v4f acc = {0.f, 0.f, 0.f, 0.f};
#pragma unroll
            for (int ko = 0; ko < 4; ko++){
                v8s b = *(const v8s*)(W1T + (size_t)(ct*16 + m) * 128 + ko*32 + q*8);
                acc = __builtin_amdgcn_mfma_f32_16x16x32_bf16(a[ko], b, acc, 0, 0, 0);
            }
            int col = ct*16 + m;
            float bv = b1[col];
#pragma unroll
            for (int r = 0; r < 4; r++){
                int lrow = w*16 + q*4 + r;
                hsh[lrow*72 + col] = f2bf(fmaxf(acc[r] + bv, 0.f));
            }
        }
    }
    // GEMM2: x_new = relu(h @ W2 + b2)
    {
        v8s a2[2];
#pragma unroll
        for (int ko = 0; ko < 2; ko++)
            a2[ko] = *(const v8s*)(&hsh[(w*16 + m)*72 + ko*32 + q*8]);
#pragma unroll
        for (int ct = 0; ct < 4; ct++){
            v4f acc = {0.f, 0.f, 0.f, 0.f};
#pragma unroll
            for (int ko = 0; ko < 2; ko++){
                v8s b = *(const v8s*)(W2T + (size_t)(ct*16 + m) * 64 + ko*32 + q*8);
                acc = __builtin_amdgcn_mfma_f32_16x16x32_bf16(a2[ko], b, acc, 0, 0, 0);
            }
            int col = ct*16 + m;
            float bv = b2[col];
#pragma unroll
            for (int r = 0; r < 4; r++){
                int orow = rbase + q*4 + r;
                if (orow < n)
                    xcb_nxt[(size_t)orow * 128 + col] = f2bf(fmaxf(acc[r] + bv, 0.f));
            }
        }
    }
}

// ---------------- global_add_pool: 16 rows per wave (latency-parallel) -----
#define PROWS 16
__global__ __launch_bounds__(64) void pool_kernel(
        const float* __restrict__ xw, const int* __restrict__ batch,
        float* __restrict__ g, int n)
{
    int lane = threadIdx.x;
    int r0 = blockIdx.x * PROWS;
    if (r0 >= n) return;
    int r1 = r0 + PROWS; if (r1 > n) r1 = n;
    float acc = 0.f;
    int cb = batch[r0];
    for (int r = r0; r < r1; r++){
        int b = batch[r];
        if (b != cb){
            atomicAdd(&g[(size_t)cb*64 + lane], acc);
            acc = 0.f; cb = b;
        }
        acc += xw[(size_t)r*64 + lane];
    }
    atomicAdd(&g[(size_t)cb*64 + lane], acc);
}

// ---------------- head ----------------------------------------------------
__global__ __launch_bounds__(256) void head_kernel(
        const float* __restrict__ g, const float* __restrict__ postW,
        const float* __restrict__ postb, const float* __restrict__ roW,
        const float* __restrict__ rob, float* __restrict__ out, int ngraph)
{
    int gr = __builtin_amdgcn_readfirstlane(blockIdx.x * 4 + (threadIdx.x >> 6));
    int lane = threadIdx.x & 63;
    if (gr >= ngraph) return;
    float gv = g[(size_t)gr*64 + lane];
    float t = postb[lane];
    for (int k = 0; k < 64; k++){
        float a = __shfl(gv, k);
        t = fmaf(a, postW[k*64 + lane], t);
    }
    t = fmaxf(t, 0.f);
    float lg = (lane < NCLS) ? rob[lane] : 0.f;
    for (int k = 0; k < 64; k++){
        float a = __shfl(t, k);
        float w = (lane < NCLS) ? roW[k*NCLS + lane] : 0.f;
        lg = fmaf(a, w, lg);
    }
    float m = (lane < NCLS) ? lg : -INFINITY;
#pragma unroll
    for (int d = 1; d < 16; d <<= 1) m = fmaxf(m, __shfl_xor(m, d, 16));
    float ex = (lane < NCLS) ? expf(lg - m) : 0.f;
    float ssum = ex;
#pragma unroll
    for (int d = 1; d < 16; d <<= 1) ssum += __shfl_xor(ssum, d, 16);
    if (lane < NCLS) out[(size_t)gr*NCLS + lane] = lg - m - logf(ssum);
}

// ---------------- launch --------------------------------------------------
extern "C" void kernel_launch(void* const* d_in, const int* in_sizes, int n_in,
                              void* d_out, int out_size, void* d_ws, size_t ws_size,
                              hipStream_t stream) {
    const float* x      = (const float*)d_in[0];
    const float* s      = (const float*)d_in[1];
    const int*   ei     = (const int*)d_in[2];    // int32
    const int*   batch  = (const int*)d_in[3];    // int32
    const float* pre_W  = (const float*)d_in[4];
    const float* pre_b  = (const float*)d_in[5];
    const float* emb_W  = (const float*)d_in[6];
    const float* emb_b  = (const float*)d_in[7];
    const float* gin_W1 = (const float*)d_in[8];
    const float* gin_b1 = (const float*)d_in[9];
    const float* gin_W2 = (const float*)d_in[10];
    const float* gin_b2 = (const float*)d_in[11];
    const float* gcn_W  = (const float*)d_in[12];
    const float* gcn_b  = (const float*)d_in[13];
    const float* whp_W  = (const float*)d_in[14];
    const float* whp_b  = (const float*)d_in[15];
    const float* post_W = (const float*)d_in[16];
    const float* post_b = (const float*)d_in[17];
    const float* ro_W   = (const float*)d_in[18];
    const float* ro_b   = (const float*)d_in[19];
    float* out = (float*)d_out;

    char* w = (char*)d_ws;
    auto alloc = [&](size_t bytes) -> void* {
        void* p = (void*)w;
        w += (bytes + 255) & ~(size_t)255;
        return p;
    };
    int*   off   = (int*)  alloc((size_t)(NN+1) * 4);
    int*   csr   = (int*)  alloc((size_t)NE * 4);
    int*   ghist = (int*)  alloc((size_t)NCH * CB * 4);
    unsigned int* ebuf = (unsigned int*)alloc((size_t)NE * 4);
    float* dinv = (float*)alloc((size_t)NN * 4);
    unsigned short* xcb0 = (unsigned short*)alloc((size_t)NN * 128 * 2);
    unsigned short* xcb1 = (unsigned short*)alloc((size_t)NN * 128 * 2);
    float* xw   = (float*)alloc((size_t)NN * 64 * 4);
    float* gbuf = (float*)alloc((size_t)NG * 64 * 4);
    unsigned short* gcnWT = (unsigned short*)alloc((size_t)3 * 4096 * 2);
    unsigned short* W1T   = (unsigned short*)alloc((size_t)3 * 8192 * 2);
    unsigned short* W2T   = (unsigned short*)alloc((size_t)3 * 4096 * 2);
    unsigned short* whpWT = (unsigned short*)alloc((size_t)8192 * 2);

    const int B  = 256;
    const int GL = (NN + 63) / 64;   // 782

    // weight prep + CSR build (196-block hist/bin)
    wprep<<<224, 256, 0, stream>>>(gcn_W, gin_W1, gin_W2, whp_W, gcnWT, W1T, W2T, whpWT);
    coarse_hist<<<NCH, 256, 0, stream>>>(ei + NE, ghist);
    coarse_scan<<<1,   256, 0, stream>>>(ghist);
    bin_lds    <<<NCH, 256, 0, stream>>>(ei, ei + NE, ghist, ebuf);
    scatter_all<<<CB,  256, 0, stream>>>(ebuf, ghist, off, dinv, csr, NN);

    // fused pre+emb -> xcb0
    pre_emb<<<GL, B, 0, stream>>>(x, pre_W, pre_b, s, emb_W, emb_b, xcb0, NN);

    // layers: one fused kernel per layer (gather + 3 MFMA GEMMs)
    for (int i = 0; i < NLAY; i++){
        unsigned short* cur = (i & 1) ? xcb1 : xcb0;
        unsigned short* nxt = (i & 1) ? xcb0 : xcb1;
        layer_fused<<<GL, B, 0, stream>>>((const unsigned int*)cur, dinv, off, csr,
                                          W1T + (size_t)i*8192, gin_b1 + i*64,
                                          W2T + (size_t)i*4096, gin_b2 + i*64,
                                          gcnWT + (size_t)i*4096, gcn_b + i*64,
                                          nxt, NN);
    }

    // whp (final state in xcb1 after 3 layers)
    mfma_linear<128><<<GL, B, 0, stream>>>(xcb1, 128, whpWT, whp_b, xw, 64, NN);

    // pool: explicit zero kernel immediately before consumer, then pool + head
    zero_f32<<<(NG*64 + B-1)/B, B, 0, stream>>>(gbuf, NG*64);
    pool_kernel<<<(NN + PROWS - 1)/PROWS, 64, 0, stream>>>(xw, batch, gbuf, NN);
    head_kernel<<<(NG + 3)/4, B, 0, stream>>>(gbuf, post_W, post_b, ro_W, ro_b, out, NG);
}

// Round 16
// 374.341 us; speedup vs baseline: 1.2637x; 1.2637x over previous
//
#include <hip/hip_runtime.h>
#include <math.h>

#define NN   50000
#define NE   800000
#define FEATD 128
#define SED  16
#define HD   64
#define NCLS 10
#define NLAY 3
#define NG   500

// two-level counting sort params
#define CHUNK 4096
#define NCH   ((NE + CHUNK - 1) / CHUNK)  // 196
#define CBSH  9
#define CB    ((NN + (1 << CBSH) - 1) >> CBSH)  // 98

typedef short  v8s __attribute__((ext_vector_type(8)));
typedef float  v4f __attribute__((ext_vector_type(4)));

// ---- bf16 helpers ---------------------------------------------------------
__device__ inline unsigned short f2bf(float f){
    unsigned int u = __float_as_uint(f);
    u += 0x7fffu + ((u >> 16) & 1u);
    return (unsigned short)(u >> 16);
}
__device__ inline unsigned int pack2bf(float a, float b){
    return (unsigned int)f2bf(a) | ((unsigned int)f2bf(b) << 16);
}
__device__ inline float bf_lo(unsigned int p){ return __uint_as_float(p << 16); }
__device__ inline float bf_hi(unsigned int p){ return __uint_as_float(p & 0xffff0000u); }

// ---------------- utility ---------------------------------------------------
__global__ void zero_f32(float* __restrict__ p, int n){
    int i = blockIdx.x*blockDim.x + threadIdx.x;
    if (i < n) p[i] = 0.f;
}

// ---------------- weight prep: bf16 + transpose to WT[n][k] ----------------
__global__ __launch_bounds__(256) void wprep(
        const float* __restrict__ gcn_W, const float* __restrict__ gin_W1,
        const float* __restrict__ gin_W2, const float* __restrict__ whp_W,
        unsigned short* __restrict__ gcnWT, unsigned short* __restrict__ W1T,
        unsigned short* __restrict__ W2T,  unsigned short* __restrict__ whpWT)
{
    int i = blockIdx.x*256 + threadIdx.x;
    if (i < 12288){
        int li = i / 4096, r = i % 4096, nn = r / 64, kk = r % 64;
        gcnWT[li*4096 + nn*64 + kk] = f2bf(gcn_W[li*4096 + kk*64 + nn]);
    } else if (i < 36864){
        int j = i - 12288; int li = j / 8192, r = j % 8192, nn = r / 128, kk = r % 128;
        W1T[li*8192 + nn*128 + kk] = f2bf(gin_W1[li*8192 + kk*64 + nn]);
    } else if (i < 49152){
        int j = i - 36864; int li = j / 4096, r = j % 4096, nn = r / 64, kk = r % 64;
        W2T[li*4096 + nn*64 + kk] = f2bf(gin_W2[li*4096 + kk*64 + nn]);
    } else if (i < 57344){
        int j = i - 49152; int nn = j / 128, kk = j % 128;
        whpWT[nn*128 + kk] = f2bf(whp_W[kk*64 + nn]);
    }
}

// ---------------- two-level counting sort of edges by dst ------------------
__global__ __launch_bounds__(256) void coarse_hist(
        const int* __restrict__ dst, int* __restrict__ ghist){
    __shared__ int h[CB];
    for (int i = threadIdx.x; i < CB; i += 256) h[i] = 0;
    __syncthreads();
    int base = blockIdx.x * CHUNK;
    int end  = base + CHUNK; if (end > NE) end = NE;
    for (int i = base + threadIdx.x; i < end; i += 256)
        atomicAdd(&h[dst[i] >> CBSH], 1);
    __syncthreads();
    for (int i = threadIdx.x; i < CB; i += 256)
        ghist[(size_t)blockIdx.x * CB + i] = h[i];
}

// LDS-staged scan of ghist (196*98 ints = 77KB LDS); single-block kernel.
__global__ __launch_bounds__(256) void coarse_scan(int* __restrict__ ghist){
    __shared__ int sh[NCH * CB];
    __shared__ int sc[256];
    int t = threadIdx.x;
    for (int i = t; i < NCH * CB; i += 256) sh[i] = ghist[i];
    __syncthreads();
    int run = 0;
    if (t < CB){
        for (int c = 0; c < NCH; c++){
            int v = sh[c*CB + t];
            sh[c*CB + t] = run;
            run += v;
        }
    }
    sc[t] = (t < CB) ? run : 0;
    __syncthreads();
    for (int d = 1; d < 256; d <<= 1){
        int u = (t >= d) ? sc[t-d] : 0;
        __syncthreads();
        sc[t] += u;
        __syncthreads();
    }
    int bstart = (t == 0) ? 0 : sc[t-1];
    if (t < CB){
        for (int c = 0; c < NCH; c++) sh[c*CB + t] += bstart;
    }
    __syncthreads();
    for (int i = t; i < NCH * CB; i += 256) ghist[i] = sh[i];
}

__global__ __launch_bounds__(256) void bin_lds(
        const int* __restrict__ src, const int* __restrict__ dst,
        const int* __restrict__ ghist, unsigned int* __restrict__ ebuf){
    __shared__ unsigned int lbuf[CHUNK];
    __shared__ unsigned int lbuf2[CHUNK];
    __shared__ int hist[CB], lstart[CB], cursor[CB], gbase[CB];
    __shared__ int sc[256];
    int t = threadIdx.x, c = blockIdx.x;
    for (int i = t; i < CB; i += 256){
        hist[i] = 0;
        gbase[i] = ghist[(size_t)c*CB + i];
    }
    __syncthreads();
    int base = c * CHUNK;
    int nend = base + CHUNK; if (nend > NE) nend = NE;
    nend -= base;
    for (int i = t; i < nend; i += 256){
        int d = dst[base + i];
        lbuf[i] = (unsigned int)src[base + i] | ((unsigned int)d << 16);
        atomicAdd(&hist[d >> CBSH], 1);
    }
    __syncthreads();
    sc[t] = (t < CB) ? hist[t] : 0;
    __syncthreads();
    for (int d = 1; d < 256; d <<= 1){
        int u = (t >= d) ? sc[t-d] : 0;
        __syncthreads();
        sc[t] += u;
        __syncthreads();
    }
    if (t < CB){
        lstart[t] = sc[t] - hist[t];
        cursor[t] = sc[t] - hist[t];
    }
    __syncthreads();
    for (int i = t; i < nend; i += 256){
        unsigned int u = lbuf[i];
        int b = (int)(u >> 16) >> CBSH;
        int p = atomicAdd(&cursor[b], 1);
        lbuf2[p] = u;
    }
    __syncthreads();
    for (int p = t; p < nend; p += 256){
        unsigned int u = lbuf2[p];
        int b = (int)(u >> 16) >> CBSH;
        ebuf[gbase[b] + (p - lstart[b])] = u;
    }
}

__global__ __launch_bounds__(256) void scatter_all(
        const unsigned int* __restrict__ ebuf, const int* __restrict__ ghist,
        int* __restrict__ off, float* __restrict__ dinv,
        int* __restrict__ csr, int n){
    __shared__ int lcnt[512];
    __shared__ int lex[512];
    __shared__ int sc[256];
    int t = threadIdx.x, b = blockIdx.x;
    int n0 = b << CBSH;
    int nn = n - n0; if (nn > 512) nn = 512;
    int lo = ghist[b];
    int hi = (b + 1 < CB) ? ghist[b + 1] : NE;
    lcnt[t] = 0; lcnt[t + 256] = 0;
    __syncthreads();
    for (int j = lo + t; j < hi; j += 256)
        atomicAdd(&lcnt[(int)(ebuf[j] >> 16) - n0], 1);
    __syncthreads();
    int c0 = lcnt[2*t], c1 = lcnt[2*t+1];
    sc[t] = c0 + c1;
    __syncthreads();
    for (int d = 1; d < 256; d <<= 1){
        int u = (t >= d) ? sc[t-d] : 0;
        __syncthreads();
        sc[t] += u;
        __syncthreads();
    }
    int bse = sc[t] - (c0 + c1);
    lex[2*t]   = bse;
    lex[2*t+1] = bse + c0;
    __syncthreads();
    for (int i = t; i < nn; i += 256){
        off[n0 + i]  = lo + lex[i];
        dinv[n0 + i] = rsqrtf((float)lcnt[i] + 1.0f);
    }
    if (b == 0 && t == 0) off[n] = NE;
    __syncthreads();
    for (int j = lo + t; j < hi; j += 256){
        unsigned int u = ebuf[j];
        int d = (int)(u >> 16) - n0;
        int p = atomicAdd(&lex[d], 1);
        csr[lo + p] = (int)(u & 0xffffu);
    }
}

// ---------------- fused pre+emb: xcb0 = bf16([x@preW+b | s@embW+b]) -------
__global__ __launch_bounds__(256) void pre_emb(
        const float* __restrict__ x, const float* __restrict__ preW,
        const float* __restrict__ preb,
        const float* __restrict__ s, const float* __restrict__ embW,
        const float* __restrict__ embb,
        unsigned short* __restrict__ xcb, int n)
{
    __shared__ float atx[64 * 132];
    __shared__ float ats[64 * 20];
    int tid = threadIdx.x;
    int r0  = blockIdx.x * 64;
    for (int idx = tid; idx < 64 * 32; idx += 256){
        int row = idx >> 5, kq = idx & 31;
        float4 v = make_float4(0.f, 0.f, 0.f, 0.f);
        if (r0 + row < n) v = *(const float4*)(x + (size_t)(r0 + row) * 128 + kq * 4);
        *(float4*)(&atx[row * 132 + kq * 4]) = v;
    }
    for (int idx = tid; idx < 64 * 4; idx += 256){
        int row = idx >> 2, kq = idx & 3;
        float4 v = make_float4(0.f, 0.f, 0.f, 0.f);
        if (r0 + row < n) v = *(const float4*)(s + (size_t)(r0 + row) * 16 + kq * 4);
        *(float4*)(&ats[row * 20 + kq * 4]) = v;
    }
    __syncthreads();
    int lane = tid & 63;
    int c0 = __builtin_amdgcn_readfirstlane((tid >> 6) << 4);
    int row = r0 + lane;
    if (row >= n) return;
    float acc[16];
#pragma unroll
    for (int j = 0; j < 16; j++) acc[j] = 0.f;
    for (int k = 0; k < 128; k += 4){
        float4 av = *(const float4*)(&atx[lane * 132 + k]);
        float aa[4] = {av.x, av.y, av.z, av.w};
#pragma unroll
        for (int kk = 0; kk < 4; kk++){
            const float* wr = preW + (k + kk) * 64 + c0;
#pragma unroll
            for (int j = 0; j < 16; j++)
                acc[j] = fmaf(aa[kk], wr[j], acc[j]);
        }
    }
#pragma unroll
    for (int j = 0; j < 16; j++) acc[j] += preb[c0 + j];
    unsigned int pk[8];
#pragma unroll
    for (int j = 0; j < 8; j++) pk[j] = pack2bf(acc[2*j], acc[2*j+1]);
    {
        unsigned short* ob = xcb + (size_t)row * 128 + c0;
        uint4 u0; u0.x = pk[0]; u0.y = pk[1]; u0.z = pk[2]; u0.w = pk[3];
        uint4 u1; u1.x = pk[4]; u1.y = pk[5]; u1.z = pk[6]; u1.w = pk[7];
        *(uint4*)(ob)     = u0;
        *(uint4*)(ob + 8) = u1;
    }
#pragma unroll
    for (int j = 0; j < 16; j++) acc[j] = 0.f;
    for (int k = 0; k < 16; k += 4){
        float4 av = *(const float4*)(&ats[lane * 20 + k]);
        float aa[4] = {av.x, av.y, av.z, av.w};
#pragma unroll
        for (int kk = 0; kk < 4; kk++){
            const float* wr = embW + (k + kk) * 64 + c0;
#pragma unroll
            for (int j = 0; j < 16; j++)
                acc[j] = fmaf(aa[kk], wr[j], acc[j]);
        }
    }
#pragma unroll
    for (int j = 0; j < 16; j++) acc[j] += embb[c0 + j];
#pragma unroll
    for (int j = 0; j < 8; j++) pk[j] = pack2bf(acc[2*j], acc[2*j+1]);
    {
        unsigned short* ob = xcb + (size_t)row * 128 + 64 + c0;
        uint4 u0; u0.x = pk[0]; u0.y = pk[1]; u0.z = pk[2]; u0.w = pk[3];
        uint4 u1; u1.x = pk[4]; u1.y = pk[5]; u1.z = pk[6]; u1.w = pk[7];
        *(uint4*)(ob)     = u0;
        *(uint4*)(ob + 8) = u1;
    }
}

// ---------------- MFMA bf16 linear (whp): out fp32 -----------------------
template<int K>
__global__ __launch_bounds__(256) void mfma_linear(
        const unsigned short* __restrict__ A, int lda,
        const unsigned short* __restrict__ WT,
        const float* __restrict__ bias,
        float* __restrict__ out, int ldo, int n)
{
    constexpr int NKO = K / 32;
    int tid = threadIdx.x;
    int w = tid >> 6, l = tid & 63;
    int m = l & 15, q = l >> 4;
    int rbase = blockIdx.x * 64 + w * 16;
    int arow  = rbase + m;
    bool valid = arow < n;
    v8s a[NKO];
#pragma unroll
    for (int ko = 0; ko < NKO; ko++){
        v8s z = {0,0,0,0,0,0,0,0};
        a[ko] = valid ? *(const v8s*)(A + (size_t)arow * lda + ko*32 + q*8) : z;
    }
#pragma unroll
    for (int ct = 0; ct < 4; ct++){
        v4f acc = {0.f, 0.f, 0.f, 0.f};
#pragma unroll
        for (int ko = 0; ko < NKO; ko++){
            v8s b = *(const v8s*)(WT + (size_t)(ct*16 + m) * K + ko*32 + q*8);
            acc = __builtin_amdgcn_mfma_f32_16x16x32_bf16(a[ko], b, acc, 0, 0, 0);
        }
        int col = ct*16 + m;
        float bv = bias ? bias[col] : 0.f;
#pragma unroll
        for (int r = 0; r < 4; r++){
            int orow = rbase + q*4 + r;
            if (orow < n) out[(size_t)orow * ldo + col] = acc[r] + bv;
        }
    }
}

// ---------------- merged aggregation: ONE gather feeds GIN + GCN -----------
// 8-edge unrolled main loop: 8 gathers + 8 dinv in flight per waitcnt drain.
__global__ __launch_bounds__(256) void merged_agg(
        const unsigned int* __restrict__ xcb_cur,
        const float* __restrict__ dinv,
        const int* __restrict__ off, const int* __restrict__ csr,
        unsigned int* __restrict__ hpreb, unsigned int* __restrict__ ub, int n)
{
    int node = __builtin_amdgcn_readfirstlane(blockIdx.x * 4 + (threadIdx.x >> 6));
    int lane = threadIdx.x & 63;
    if (node >= n) return;
    int beg = off[node], end = off[node+1];
    unsigned int ps = xcb_cur[(size_t)node*64 + lane];
    float s0f = bf_lo(ps), s1f = bf_hi(ps);
    float a0 = s0f, a1 = s1f;
    float g0 = 0.f, g1 = 0.f;
    int e = beg;
    for (; e + 8 <= end; e += 8){
        int s0 = csr[e],   s1 = csr[e+1], s2 = csr[e+2], s3 = csr[e+3];
        int s4 = csr[e+4], s5 = csr[e+5], s6 = csr[e+6], s7 = csr[e+7];
        unsigned int p0 = xcb_cur[(size_t)s0*64 + lane];
        unsigned int p1 = xcb_cur[(size_t)s1*64 + lane];
        unsigned int p2 = xcb_cur[(size_t)s2*64 + lane];
        unsigned int p3 = xcb_cur[(size_t)s3*64 + lane];
        unsigned int p4 = xcb_cur[(size_t)s4*64 + lane];
        unsigned int p5 = xcb_cur[(size_t)s5*64 + lane];
        unsigned int p6 = xcb_cur[(size_t)s6*64 + lane];
        unsigned int p7 = xcb_cur[(size_t)s7*64 + lane];
        float d0 = dinv[s0], d1 = dinv[s1], d2 = dinv[s2], d3 = dinv[s3];
        float d4 = dinv[s4], d5 = dinv[s5], d6 = dinv[s6], d7 = dinv[s7];
        float v0 = bf_lo(p0), v1 = bf_lo(p1), v2 = bf_lo(p2), v3 = bf_lo(p3);
        float v4 = bf_lo(p4), v5 = bf_lo(p5), v6 = bf_lo(p6), v7 = bf_lo(p7);
        float w0 = bf_hi(p0), w1 = bf_hi(p1), w2 = bf_hi(p2), w3 = bf_hi(p3);
        float w4 = bf_hi(p4), w5 = bf_hi(p5), w6 = bf_hi(p6), w7 = bf_hi(p7);
        a0 += ((v0 + v1) + (v2 + v3)) + ((v4 + v5) + (v6 + v7));
        a1 += ((w0 + w1) + (w2 + w3)) + ((w4 + w5) + (w6 + w7));
        float ga = fmaf(d0, v0, fmaf(d1, v1, fmaf(d2, v2, d3*v3)));
        float gb = fmaf(d4, v4, fmaf(d5, v5, fmaf(d6, v6, d7*v7)));
        g0 += ga + gb;
        float gc = fmaf(d0, w0, fmaf(d1, w1, fmaf(d2, w2, d3*w3)));
        float gd = fmaf(d4, w4, fmaf(d5, w5, fmaf(d6, w6, d7*w7)));
        g1 += gc + gd;
    }
    for (; e + 4 <= end; e += 4){
        int s0 = csr[e], s1 = csr[e+1], s2 = csr[e+2], s3 = csr[e+3];
        unsigned int p0 = xcb_cur[(size_t)s0*64 + lane];
        unsigned int p1 = xcb_cur[(size_t)s1*64 + lane];
        unsigned int p2 = xcb_cur[(size_t)s2*64 + lane];
        unsigned int p3 = xcb_cur[(size_t)s3*64 + lane];
        float d0 = dinv[s0], d1 = dinv[s1], d2 = dinv[s2], d3 = dinv[s3];
        float v0 = bf_lo(p0), v1 = bf_lo(p1), v2 = bf_lo(p2), v3 = bf_lo(p3);
        float w0 = bf_hi(p0), w1 = bf_hi(p1), w2 = bf_hi(p2), w3 = bf_hi(p3);
        a0 += (v0 + v1) + (v2 + v3);
        a1 += (w0 + w1) + (w2 + w3);
        g0 = fmaf(d0, v0, fmaf(d1, v1, fmaf(d2, v2, fmaf(d3, v3, g0))));
        g1 = fmaf(d0, w0, fmaf(d1, w1, fmaf(d2, w2, fmaf(d3, w3, g1))));
    }
    for (; e < end; e++){
        int s0 = csr[e];
        unsigned int p0 = xcb_cur[(size_t)s0*64 + lane];
        float d0 = dinv[s0];
        float v0 = bf_lo(p0), w0 = bf_hi(p0);
        a0 += v0; a1 += w0;
        g0 = fmaf(d0, v0, g0);
        g1 = fmaf(d0, w0, g1);
    }
    hpreb[(size_t)node*64 + lane] = pack2bf(a0, a1);
    if (lane >= 32){   // lanes 32..63 hold s_prev cols (64..127)
        float di = dinv[node];
        float u0 = fmaf(di, g0, di*di*s0f);
        float u1 = fmaf(di, g1, di*di*s1f);
        ub[(size_t)node*32 + (lane - 32)] = pack2bf(u0, u1);
    }
}

// ---------------- fused per-layer MFMA: GIN MLP + GCN linear ---------------
__global__ __launch_bounds__(256) void ginmlp3(
        const unsigned short* __restrict__ hpreb,   // [n,128] bf16
        const unsigned short* __restrict__ ub,      // [n,64]  bf16
        const unsigned short* __restrict__ W1T,     // [64][128]
        const float* __restrict__ b1,
        const unsigned short* __restrict__ W2T,     // [64][64]
        const float* __restrict__ b2,
        const unsigned short* __restrict__ gcnWT,   // [64][64]
        const float* __restrict__ gcnb,
        unsigned short* __restrict__ xcb_nxt, int n)
{
    __shared__ unsigned short hsh[64 * 72];
    int tid = threadIdx.x;
    int w = tid >> 6, l = tid & 63;
    int m = l & 15, q = l >> 4;
    int rbase = blockIdx.x * 64 + w * 16;
    int arow  = rbase + m;
    bool valid = arow < n;
    v8s z = {0,0,0,0,0,0,0,0};
    // GEMM3: s_new = tanh(ub @ gcnW + b)
    {
        v8s a3[2];
#pragma unroll
        for (int ko = 0; ko < 2; ko++)
            a3[ko] = valid ? *(const v8s*)(ub + (size_t)arow * 64 + ko*32 + q*8) : z;
#pragma unroll
        for (int ct = 0; ct < 4; ct++){
            v4f acc = {0.f, 0.f, 0.f, 0.f};
#pragma unroll
            for (int ko = 0; ko < 2; ko++){
                v8s b = *(const v8s*)(gcnWT + (size_t)(ct*16 + m) * 64 + ko*32 + q*8);
                acc = __builtin_amdgcn_mfma_f32_16x16x32_bf16(a3[ko], b, acc, 0, 0, 0);
            }
            int col = ct*16 + m;
            float bv = gcnb[col];
#pragma unroll
            for (int r = 0; r < 4; r++){
                int orow = rbase + q*4 + r;
                if (orow < n)
                    xcb_nxt[(size_t)orow * 128 + 64 + col] = f2bf(tanhf(acc[r] + bv));
            }
        }
    }
    // GEMM1: h = relu(hpreb @ W1 + b1) -> LDS (bf16)
    {
        v8s a[4];
#pragma unroll
        for (int ko = 0; ko < 4; ko++)
            a[ko] = valid ? *(const v8s*)(hpreb + (size_t)arow * 128 + ko*32 + q*8) : z;
#pragma unroll
        for (int ct = 0; ct < 4; ct++){
            v4f acc = {0.f, 0.f, 0.f, 0.f};
#pragma unroll
            for (int ko = 0; ko < 4; ko++){
                v8s b = *(const v8s*)(W1T + (size_t)(ct*16 + m) * 128 + ko*32 + q*8);
                acc = __builtin_amdgcn_mfma_f32_16x16x32_bf16(a[ko], b, acc, 0, 0, 0);
            }
            int col = ct*16 + m;
            float bv = b1[col];
#pragma unroll
            for (int r = 0; r < 4; r++){
                int lrow = w*16 + q*4 + r;
                hsh[lrow*72 + col] = f2bf(fmaxf(acc[r] + bv, 0.f));
            }
        }
    }
    __syncthreads();
    // GEMM2: x_new = relu(h @ W2 + b2)
    v8s a2[2];
#pragma unroll
    for (int ko = 0; ko < 2; ko++)
        a2[ko] = *(const v8s*)(&hsh[(w*16 + m)*72 + ko*32 + q*8]);
#pragma unroll
    for (int ct = 0; ct < 4; ct++){
        v4f acc = {0.f, 0.f, 0.f, 0.f};
#pragma unroll
        for (int ko = 0; ko < 2; ko++){
            v8s b = *(const v8s*)(W2T + (size_t)(ct*16 + m) * 64 + ko*32 + q*8);
            acc = __builtin_amdgcn_mfma_f32_16x16x32_bf16(a2[ko], b, acc, 0, 0, 0);
        }
        int col = ct*16 + m;
        float bv = b2[col];
#pragma unroll
        for (int r = 0; r < 4; r++){
            int orow = rbase + q*4 + r;
            if (orow < n)
                xcb_nxt[(size_t)orow * 128 + col] = f2bf(fmaxf(acc[r] + bv, 0.f));
        }
    }
}

// ---------------- global_add_pool: 16 rows per wave (latency-parallel) -----
#define PROWS 16
__global__ __launch_bounds__(64) void pool_kernel(
        const float* __restrict__ xw, const int* __restrict__ batch,
        float* __restrict__ g, int n)
{
    int lane = threadIdx.x;
    int r0 = blockIdx.x * PROWS;
    if (r0 >= n) return;
    int r1 = r0 + PROWS; if (r1 > n) r1 = n;
    float acc = 0.f;
    int cb = batch[r0];
    for (int r = r0; r < r1; r++){
        int b = batch[r];
        if (b != cb){
            atomicAdd(&g[(size_t)cb*64 + lane], acc);
            acc = 0.f; cb = b;
        }
        acc += xw[(size_t)r*64 + lane];
    }
    atomicAdd(&g[(size_t)cb*64 + lane], acc);
}

// ---------------- head ----------------------------------------------------
__global__ __launch_bounds__(256) void head_kernel(
        const float* __restrict__ g, const float* __restrict__ postW,
        const float* __restrict__ postb, const float* __restrict__ roW,
        const float* __restrict__ rob, float* __restrict__ out, int ngraph)
{
    int gr = __builtin_amdgcn_readfirstlane(blockIdx.x * 4 + (threadIdx.x >> 6));
    int lane = threadIdx.x & 63;
    if (gr >= ngraph) return;
    float gv = g[(size_t)gr*64 + lane];
    float t = postb[lane];
    for (int k = 0; k < 64; k++){
        float a = __shfl(gv, k);
        t = fmaf(a, postW[k*64 + lane], t);
    }
    t = fmaxf(t, 0.f);
    float lg = (lane < NCLS) ? rob[lane] : 0.f;
    for (int k = 0; k < 64; k++){
        float a = __shfl(t, k);
        float w = (lane < NCLS) ? roW[k*NCLS + lane] : 0.f;
        lg = fmaf(a, w, lg);
    }
    float m = (lane < NCLS) ? lg : -INFINITY;
#pragma unroll
    for (int d = 1; d < 16; d <<= 1) m = fmaxf(m, __shfl_xor(m, d, 16));
    float ex = (lane < NCLS) ? expf(lg - m) : 0.f;
    float ssum = ex;
#pragma unroll
    for (int d = 1; d < 16; d <<= 1) ssum += __shfl_xor(ssum, d, 16);
    if (lane < NCLS) out[(size_t)gr*NCLS + lane] = lg - m - logf(ssum);
}

// ---------------- launch --------------------------------------------------
extern "C" void kernel_launch(void* const* d_in, const int* in_sizes, int n_in,
                              void* d_out, int out_size, void* d_ws, size_t ws_size,
                              hipStream_t stream) {
    const float* x      = (const float*)d_in[0];
    const float* s      = (const float*)d_in[1];
    const int*   ei     = (const int*)d_in[2];    // int32
    const int*   batch  = (const int*)d_in[3];    // int32
    const float* pre_W  = (const float*)d_in[4];
    const float* pre_b  = (const float*)d_in[5];
    const float* emb_W  = (const float*)d_in[6];
    const float* emb_b  = (const float*)d_in[7];
    const float* gin_W1 = (const float*)d_in[8];
    const float* gin_b1 = (const float*)d_in[9];
    const float* gin_W2 = (const float*)d_in[10];
    const float* gin_b2 = (const float*)d_in[11];
    const float* gcn_W  = (const float*)d_in[12];
    const float* gcn_b  = (const float*)d_in[13];
    const float* whp_W  = (const float*)d_in[14];
    const float* whp_b  = (const float*)d_in[15];
    const float* post_W = (const float*)d_in[16];
    const float* post_b = (const float*)d_in[17];
    const float* ro_W   = (const float*)d_in[18];
    const float* ro_b   = (const float*)d_in[19];
    float* out = (float*)d_out;

    char* w = (char*)d_ws;
    auto alloc = [&](size_t bytes) -> void* {
        void* p = (void*)w;
        w += (bytes + 255) & ~(size_t)255;
        return p;
    };
    int*   off   = (int*)  alloc((size_t)(NN+1) * 4);
    int*   csr   = (int*)  alloc((size_t)NE * 4);
    int*   ghist = (int*)  alloc((size_t)NCH * CB * 4);
    unsigned int* ebuf = (unsigned int*)alloc((size_t)NE * 4);
    float* dinv = (float*)alloc((size_t)NN * 4);
    unsigned short* xcb0 = (unsigned short*)alloc((size_t)NN * 128 * 2);
    unsigned short* xcb1 = (unsigned short*)alloc((size_t)NN * 128 * 2);
    unsigned int*   hpreb = (unsigned int*)alloc((size_t)NN * 64 * 4);  // bf16 [n,128]
    unsigned int*   ub    = (unsigned int*)alloc((size_t)NN * 32 * 4);  // bf16 [n,64]
    float* xw   = (float*)alloc((size_t)NN * 64 * 4);
    float* gbuf = (float*)alloc((size_t)NG * 64 * 4);
    unsigned short* gcnWT = (unsigned short*)alloc((size_t)3 * 4096 * 2);
    unsigned short* W1T   = (unsigned short*)alloc((size_t)3 * 8192 * 2);
    unsigned short* W2T   = (unsigned short*)alloc((size_t)3 * 4096 * 2);
    unsigned short* whpWT = (unsigned short*)alloc((size_t)8192 * 2);

    const int B  = 256;
    const int GL = (NN + 63) / 64;   // 782
    const int GA = (NN + 3) / 4;     // 12500

    // weight prep + CSR build (196-block hist/bin)
    wprep<<<224, 256, 0, stream>>>(gcn_W, gin_W1, gin_W2, whp_W, gcnWT, W1T, W2T, whpWT);
    coarse_hist<<<NCH, 256, 0, stream>>>(ei + NE, ghist);
    coarse_scan<<<1,   256, 0, stream>>>(ghist);
    bin_lds    <<<NCH, 256, 0, stream>>>(ei, ei + NE, ghist, ebuf);
    scatter_all<<<CB,  256, 0, stream>>>(ebuf, ghist, off, dinv, csr, NN);

    // fused pre+emb -> xcb0
    pre_emb<<<GL, B, 0, stream>>>(x, pre_W, pre_b, s, emb_W, emb_b, xcb0, NN);

    for (int i = 0; i < NLAY; i++){
        unsigned short* cur = (i & 1) ? xcb1 : xcb0;
        unsigned short* nxt = (i & 1) ? xcb0 : xcb1;
        merged_agg<<<GA, B, 0, stream>>>((const unsigned int*)cur, dinv, off, csr,
                                         hpreb, ub, NN);
        ginmlp3<<<GL, B, 0, stream>>>((const unsigned short*)hpreb,
                                      (const unsigned short*)ub,
                                      W1T + (size_t)i*8192, gin_b1 + i*64,
                                      W2T + (size_t)i*4096, gin_b2 + i*64,
                                      gcnWT + (size_t)i*4096, gcn_b + i*64,
                                      nxt, NN);
    }

    // whp (final state in xcb1 after 3 layers)
    mfma_linear<128><<<GL, B, 0, stream>>>(xcb1, 128, whpWT, whp_b, xw, 64, NN);

    // pool: explicit zero kernel immediately before consumer, then pool + head
    zero_f32<<<(NG*64 + B-1)/B, B, 0, stream>>>(gbuf, NG*64);
    pool_kernel<<<(NN + PROWS - 1)/PROWS, 64, 0, stream>>>(xw, batch, gbuf, NN);
    head_kernel<<<(NG + 3)/4, B, 0, stream>>>(gbuf, post_W, post_b, ro_W, ro_b, out, NG);
}